// Round 7
// baseline (1353.463 us; speedup 1.0000x reference)
//
#include <hip/hip_runtime.h>
#include <math.h>

// MarketRegimeHMM forward via chunked associative scan — linear-domain semiring,
// base-2 scales, ROW-STREAMED E build (R6):
//   E = softmax(logits)*diag(exp2(le-c)) is generated ONE ROW AT A TIME (row k
//   = state-k net) and folded into the running chunk product as an outer-
//   product accumulation R'[i][j] += R[i][k]*Erow[j].  E never exists as 25
//   live floats -> live set ~95 regs -> no scratch spill (R5's pair-build
//   spilled: WRITE_SIZE +32MB).  bf16 packing happens per-row into 13 u32.
//
//   k_prep  : 1 block; preprocess ~713 params into ws.
//   k_build : one lane per chunk (C=4), params in 3KB LDS, 4 row-streamed
//             steps, rescale-by-max after each fold; writes R[b][c] + bf16 E.
//   k_scan  : one block per b: 3-level scan over 1024 records -> start, LL.
//   k_alpha : one lane per chunk: stream bf16 E, 25 FMA + 5 log2 per t.

namespace {

constexpr int kS = 5, kD = 16, kB = 256, kT = 4096;
constexpr int kC = 4, kNC = 1024;  // chunks per batch element

constexpr float kL2E = 1.4426950408889634f;  // 1/ln2
constexpr float kLn2 = 0.6931471805599453f;

// prep region offsets (floats)
constexpr int P_EA = 0;    // 80  -0.5*inv_v/ln2            [s*16+d]
constexpr int P_MU = 80;   // 80  means (raw)               [s*16+d]
constexpr int P_EC = 160;  // 5   -0.5*(16ln2pi + sum lv)/ln2
constexpr int P_LN = 168;  // 5   log2_softmax(log_initial)
constexpr int P_W1 = 176;  // 200 (2/ln2)*W1                [(i*10+h)*4+f]
constexpr int P_B1 = 376;  // 50  (2/ln2)*b1                [i*10+h]
constexpr int P_W2 = 432;  // 250 W2/ln2                    [(i*5+j)*10+h]
constexpr int P_B2 = 688;  // 25  (b2+tbias)/ln2            [i*5+j]
constexpr int P_TOT = 768;   // staged floats (3KB)
constexpr int P_RSV = 1024;  // reserved in ws

__device__ __forceinline__ float max5(float a0, float a1, float a2, float a3, float a4) {
  return fmaxf(fmaxf(fmaxf(a0, a1), fmaxf(a2, a3)), a4);
}

__device__ __forceinline__ void loadObs(const float* __restrict__ obs_bt, float* o) {
  const float4* o4 = reinterpret_cast<const float4*>(obs_bt);
  float4 v0 = o4[0], v1 = o4[1], v2 = o4[2], v3 = o4[3];
  o[0] = v0.x; o[1] = v0.y; o[2] = v0.z; o[3] = v0.w;
  o[4] = v1.x; o[5] = v1.y; o[6] = v1.z; o[7] = v1.w;
  o[8] = v2.x; o[9] = v2.y; o[10] = v2.z; o[11] = v2.w;
  o[12] = v3.x; o[13] = v3.y; o[14] = v3.z; o[15] = v3.w;
}

__device__ __forceinline__ unsigned bf16bits(float x) {
  unsigned u = __float_as_uint(x);
  return (u + 0x7fffu + ((u >> 16) & 1u)) >> 16;  // RTNE
}

__global__ void k_prep(const float* __restrict__ means, const float* __restrict__ lv,
                       const float* __restrict__ linit, const float* __restrict__ tbias,
                       const float* __restrict__ W1g, const float* __restrict__ b1g,
                       const float* __restrict__ W2g, const float* __restrict__ b2g,
                       float* __restrict__ P) {
  const int tid = threadIdx.x;  // 256
  if (tid < 80) {
    float iv = __expf(-lv[tid]);
    P[P_EA + tid] = -0.5f * kL2E * iv;
    P[P_MU + tid] = means[tid];
  }
  if (tid >= 80 && tid < 85) {
    const int s = tid - 80;
    float acc = 0.f;
#pragma unroll
    for (int d = 0; d < 16; ++d) acc += lv[s * 16 + d];
    P[P_EC + s] = -0.5f * kL2E * (29.406033062549525f + acc);  // 16*ln(2pi)+sum
    float l0 = linit[0], l1 = linit[1], l2 = linit[2], l3 = linit[3], l4 = linit[4];
    float m = max5(l0, l1, l2, l3, l4);
    float se = __expf(l0 - m) + __expf(l1 - m) + __expf(l2 - m) +
               __expf(l3 - m) + __expf(l4 - m);
    P[P_LN + s] = kL2E * (linit[s] - (m + __logf(se)));
  }
  if (tid < 200) P[P_W1 + tid] = (2.0f * kL2E) * W1g[tid];
  if (tid < 50)  P[P_B1 + tid] = (2.0f * kL2E) * b1g[tid];
  if (tid < 250) P[P_W2 + tid] = kL2E * W2g[tid];
  if (tid < 25)  P[P_B2 + tid] = kL2E * (b2g[tid] + tbias[tid]);
  if (tid >= 225 && tid < 225 + (P_TOT - 713)) {
    P[713 + tid - 225] = 0.f;  // pad so the LDS float4 stage reads defined data
  }
}

// One timestep, row-streamed: builds E row-by-row, folds into Rout.
// MODE 0: Rout = E.  MODE 1: Rout = Rin x E (outer-product accumulation).
// Returns c (log2 emission scale); if STORE, writes packed bf16 E + c to wsE.
template <int MODE, bool STORE>
__device__ __forceinline__ float stepE(const float* __restrict__ obs,
                                       const float* __restrict__ feat,
                                       const float* __restrict__ p,
                                       size_t t, const float* __restrict__ Rin,
                                       float* __restrict__ Rout,
                                       uint4* __restrict__ wsE) {
  float o[16];
  loadObs(obs + t * kD, o);
  float le[5];
#pragma unroll
  for (int s = 0; s < 5; ++s) {
    float acc = p[P_EC + s];
#pragma unroll
    for (int d = 0; d < 16; ++d) {
      const float dd = o[d] - p[P_MU + s * 16 + d];
      acc = fmaf(dd, dd * p[P_EA + s * 16 + d], acc);
    }
    le[s] = acc;
  }
  const float c = max5(le[0], le[1], le[2], le[3], le[4]);
  float eml[5];
#pragma unroll
  for (int j = 0; j < 5; ++j) eml[j] = exp2f(le[j] - c);
  const float4 f = *reinterpret_cast<const float4*>(feat + t * 4);
  unsigned eb[13];
#pragma unroll
  for (int k = 0; k < 5; ++k) {
    float hv[10];
#pragma unroll
    for (int h = 0; h < 10; ++h) {
      float acc = p[P_B1 + k * 10 + h];
      acc = fmaf(f.x, p[P_W1 + (k * 10 + h) * 4 + 0], acc);
      acc = fmaf(f.y, p[P_W1 + (k * 10 + h) * 4 + 1], acc);
      acc = fmaf(f.z, p[P_W1 + (k * 10 + h) * 4 + 2], acc);
      acc = fmaf(f.w, p[P_W1 + (k * 10 + h) * 4 + 3], acc);
      const float e = exp2f(acc);                            // = exp(2x)
      hv[h] = 1.f - 2.f * __builtin_amdgcn_rcpf(e + 1.f);    // tanh
    }
    float eg[5], se = 0.f;
#pragma unroll
    for (int j = 0; j < 5; ++j) {
      float acc = p[P_B2 + k * 5 + j];
#pragma unroll
      for (int h = 0; h < 10; ++h)
        acc = fmaf(hv[h], p[P_W2 + (k * 5 + j) * 10 + h], acc);
      eg[j] = exp2f(acc);
      se += eg[j];
    }
    const float rs = __builtin_amdgcn_rcpf(se);
    float er[5];
#pragma unroll
    for (int j = 0; j < 5; ++j) er[j] = eg[j] * rs * eml[j];
    if (STORE) {
#pragma unroll
      for (int j = 0; j < 5; ++j) {
        const int sl = 5 * k + j;
        const unsigned bits = bf16bits(er[j]);
        if (sl & 1) eb[sl >> 1] |= bits << 16;
        else        eb[sl >> 1] = bits;
      }
    }
    if (MODE == 0) {
#pragma unroll
      for (int j = 0; j < 5; ++j) Rout[k * 5 + j] = er[j];
    } else {
#pragma unroll
      for (int i = 0; i < 5; ++i) {
#pragma unroll
        for (int j = 0; j < 5; ++j) {
          if (k == 0) Rout[i * 5 + j] = Rin[i * 5 + 0] * er[j];
          else Rout[i * 5 + j] = fmaf(Rin[i * 5 + k], er[j], Rout[i * 5 + j]);
        }
      }
    }
  }
  if (STORE) {
    const unsigned cb = __float_as_uint(c);
    eb[12] |= cb << 16;
    uint4* wp = wsE + t * 4;
    wp[0] = make_uint4(eb[0], eb[1], eb[2], eb[3]);
    wp[1] = make_uint4(eb[4], eb[5], eb[6], eb[7]);
    wp[2] = make_uint4(eb[8], eb[9], eb[10], eb[11]);
    wp[3] = make_uint4(eb[12], cb >> 16, 0u, 0u);
  }
  return c;
}

// t=0 pseudo-record: rows all equal alpha0 (log2-scaled); Rout = E0.
template <bool STORE>
__device__ __forceinline__ float stepE0(const float* __restrict__ obs,
                                        const float* __restrict__ p, int b,
                                        float* __restrict__ Rout,
                                        uint4* __restrict__ wsE) {
  float o[16];
  loadObs(obs + (size_t)b * kT * kD, o);
  float v[5];
#pragma unroll
  for (int s = 0; s < 5; ++s) {
    float acc = p[P_EC + s];
#pragma unroll
    for (int d = 0; d < 16; ++d) {
      const float dd = o[d] - p[P_MU + s * 16 + d];
      acc = fmaf(dd, dd * p[P_EA + s * 16 + d], acc);
    }
    v[s] = acc + p[P_LN + s];
  }
  const float c = max5(v[0], v[1], v[2], v[3], v[4]);
  float e5[5];
#pragma unroll
  for (int j = 0; j < 5; ++j) e5[j] = 0.2f * exp2f(v[j] - c);
#pragma unroll
  for (int i = 0; i < 5; ++i)
#pragma unroll
    for (int j = 0; j < 5; ++j) Rout[i * 5 + j] = e5[j];
  if (STORE) {
    unsigned eb[13];
#pragma unroll
    for (int sl = 0; sl < 25; ++sl) {
      const unsigned bits = bf16bits(e5[sl % 5]);
      if (sl & 1) eb[sl >> 1] |= bits << 16;
      else        eb[sl >> 1] = bits;
    }
    const unsigned cb = __float_as_uint(c);
    eb[12] |= cb << 16;
    uint4* wp = wsE + (size_t)b * kT * 4;
    wp[0] = make_uint4(eb[0], eb[1], eb[2], eb[3]);
    wp[1] = make_uint4(eb[4], eb[5], eb[6], eb[7]);
    wp[2] = make_uint4(eb[8], eb[9], eb[10], eb[11]);
    wp[3] = make_uint4(eb[12], cb >> 16, 0u, 0u);
  }
  return c;
}

__device__ __forceinline__ void rescale25(float R[25], float& sc) {
  float m = R[0];
#pragma unroll
  for (int e = 1; e < 25; ++e) m = fmaxf(m, R[e]);
  m = fmaxf(m, 1e-30f);
  const float r = __builtin_amdgcn_rcpf(m);
#pragma unroll
  for (int e = 0; e < 25; ++e) R[e] *= r;
  sc += __log2f(m);
}

__device__ __forceinline__ void matmat5(float R[25], const float E[25]) {
#pragma unroll
  for (int i = 0; i < 5; ++i) {
    const float r0 = R[i * 5 + 0], r1 = R[i * 5 + 1], r2 = R[i * 5 + 2];
    const float r3 = R[i * 5 + 3], r4 = R[i * 5 + 4];
#pragma unroll
    for (int j = 0; j < 5; ++j) {
      float acc = r0 * E[j];
      acc = fmaf(r1, E[5 + j], acc);
      acc = fmaf(r2, E[10 + j], acc);
      acc = fmaf(r3, E[15 + j], acc);
      acc = fmaf(r4, E[20 + j], acc);
      R[i * 5 + j] = acc;
    }
  }
}

__device__ __forceinline__ void vecmat5(float a[5], const float M[25]) {
  float o[5];
#pragma unroll
  for (int j = 0; j < 5; ++j) {
    float acc = a[0] * M[j];
    acc = fmaf(a[1], M[5 + j], acc);
    acc = fmaf(a[2], M[10 + j], acc);
    acc = fmaf(a[3], M[15 + j], acc);
    acc = fmaf(a[4], M[20 + j], acc);
    o[j] = acc;
  }
#pragma unroll
  for (int j = 0; j < 5; ++j) a[j] = o[j];
}

__device__ __forceinline__ void rescale5(float a[5], float& ls) {
  const float m = fmaxf(max5(a[0], a[1], a[2], a[3], a[4]), 1e-30f);
  const float r = __builtin_amdgcn_rcpf(m);
#pragma unroll
  for (int j = 0; j < 5; ++j) a[j] *= r;
  ls += __log2f(m);
}

template <bool STORE_E>
__global__ __launch_bounds__(256, 3) void k_build(
    const float* __restrict__ obs, const float* __restrict__ feat,
    const float* __restrict__ P, float* __restrict__ Rg,
    uint4* __restrict__ wsE) {
  __shared__ __align__(16) float p[P_TOT];
  if (threadIdx.x < P_TOT / 4)
    reinterpret_cast<float4*>(p)[threadIdx.x] =
        reinterpret_cast<const float4*>(P)[threadIdx.x];
  __syncthreads();
  const int gc = blockIdx.x * 256 + threadIdx.x;  // chunk id
  const int b = gc >> 10, cc = gc & (kNC - 1);
  const size_t t0 = (size_t)b * kT + (size_t)cc * kC;
  float Ra[25], Rb[25];
  float sc;
  if (cc == 0) sc = stepE0<STORE_E>(obs, p, b, Ra, wsE);
  else sc = stepE<0, STORE_E>(obs, feat, p, t0, Ra, Ra, wsE);
  sc += stepE<1, STORE_E>(obs, feat, p, t0 + 1, Ra, Rb, wsE);
  rescale25(Rb, sc);
  sc += stepE<1, STORE_E>(obs, feat, p, t0 + 2, Rb, Ra, wsE);
  rescale25(Ra, sc);
  sc += stepE<1, STORE_E>(obs, feat, p, t0 + 3, Ra, Rb, wsE);
  rescale25(Rb, sc);
  float4* o4 = reinterpret_cast<float4*>(Rg + (size_t)gc * 28);
  o4[0] = make_float4(Rb[0], Rb[1], Rb[2], Rb[3]);
  o4[1] = make_float4(Rb[4], Rb[5], Rb[6], Rb[7]);
  o4[2] = make_float4(Rb[8], Rb[9], Rb[10], Rb[11]);
  o4[3] = make_float4(Rb[12], Rb[13], Rb[14], Rb[15]);
  o4[4] = make_float4(Rb[16], Rb[17], Rb[18], Rb[19]);
  o4[5] = make_float4(Rb[20], Rb[21], Rb[22], Rb[23]);
  o4[6] = make_float4(Rb[24], sc, 0.f, 0.f);
}

__device__ __forceinline__ void loadRec(const float* __restrict__ base, size_t rec,
                                        float M[25], float& msc) {
  const float4* src = reinterpret_cast<const float4*>(base + rec * 28);
  float4 q[7];
#pragma unroll
  for (int i = 0; i < 7; ++i) q[i] = src[i];
  const float* v = reinterpret_cast<const float*>(q);
#pragma unroll
  for (int e = 0; e < 25; ++e) M[e] = v[e];
  msc = v[25];
}

// 3-level scan over 1024 records per b -> start[b][c], LL[b].
__global__ __launch_bounds__(256) void k_scan(const float* __restrict__ Rg,
                                              float* __restrict__ start,
                                              float* __restrict__ out) {
  __shared__ float sA[256 * 29];
  __shared__ float sB[32 * 28];
  __shared__ float sPB[32 * 8];
  __shared__ float sPA[256 * 8];
  const int b = blockIdx.x, j = threadIdx.x;
  const float* Rb = Rg + (size_t)b * kNC * 28;
  float A[25], asc;
  loadRec(Rb, (size_t)(4 * j), A, asc);
#pragma unroll 1
  for (int k = 1; k < 4; ++k) {
    float M[25], msc;
    loadRec(Rb, (size_t)(4 * j + k), M, msc);
    asc += msc;
    matmat5(A, M);
    if (k >= 2) rescale25(A, asc);
  }
#pragma unroll
  for (int e = 0; e < 25; ++e) sA[j * 29 + e] = A[e];
  sA[j * 29 + 25] = asc;
  __syncthreads();
  if (j < 32) {
    float Bm[25], bsc;
#pragma unroll
    for (int e = 0; e < 25; ++e) Bm[e] = sA[(8 * j) * 29 + e];
    bsc = sA[(8 * j) * 29 + 25];
#pragma unroll 1
    for (int k = 1; k < 8; ++k) {
      float M[25];
#pragma unroll
      for (int e = 0; e < 25; ++e) M[e] = sA[(8 * j + k) * 29 + e];
      bsc += sA[(8 * j + k) * 29 + 25];
      matmat5(Bm, M);
      if (k & 1) rescale25(Bm, bsc);
    }
#pragma unroll
    for (int e = 0; e < 25; ++e) sB[j * 28 + e] = Bm[e];
    sB[j * 28 + 25] = bsc;
  }
  __syncthreads();
  if (j == 0) {
    float a[5] = {1.f, 1.f, 1.f, 1.f, 1.f};
    float ls = 0.f;
#pragma unroll 1
    for (int g = 0; g < 32; ++g) {
#pragma unroll
      for (int s = 0; s < 5; ++s) sPB[g * 8 + s] = a[s];
      sPB[g * 8 + 5] = ls;
      float M[25];
#pragma unroll
      for (int e = 0; e < 25; ++e) M[e] = sB[g * 28 + e];
      vecmat5(a, M);
      ls += sB[g * 28 + 25];
      rescale5(a, ls);
    }
    out[b] = (__log2f(a[0] + a[1] + a[2] + a[3] + a[4]) + ls) * kLn2;
  }
  __syncthreads();
  if (j < 32) {
    float a[5], ls;
#pragma unroll
    for (int s = 0; s < 5; ++s) a[s] = sPB[j * 8 + s];
    ls = sPB[j * 8 + 5];
#pragma unroll 1
    for (int q = 0; q < 8; ++q) {
      const int idx = 8 * j + q;
#pragma unroll
      for (int s = 0; s < 5; ++s) sPA[idx * 8 + s] = a[s];
      sPA[idx * 8 + 5] = ls;
      float M[25];
#pragma unroll
      for (int e = 0; e < 25; ++e) M[e] = sA[idx * 29 + e];
      vecmat5(a, M);
      ls += sA[idx * 29 + 25];
      rescale5(a, ls);
    }
  }
  __syncthreads();
  {
    float a[5], ls;
#pragma unroll
    for (int s = 0; s < 5; ++s) a[s] = sPA[j * 8 + s];
    ls = sPA[j * 8 + 5];
#pragma unroll 1
    for (int k = 0; k < 4; ++k) {
      const int r = 4 * j + k;
      float* st = start + ((size_t)b * kNC + r) * 8;
      reinterpret_cast<float4*>(st)[0] = make_float4(a[0], a[1], a[2], a[3]);
      reinterpret_cast<float4*>(st)[1] = make_float4(a[4], ls, 0.f, 0.f);
      float M[25], msc;
      loadRec(Rb, (size_t)r, M, msc);
      vecmat5(a, M);
      ls += msc;
      rescale5(a, ls);
    }
  }
}

// stream bf16 E records; one lane per chunk
__global__ __launch_bounds__(256) void k_alpha_a(const uint4* __restrict__ wsE,
                                                 const float* __restrict__ start,
                                                 float* __restrict__ outp) {
  const int gc = blockIdx.x * 256 + threadIdx.x;
  const int b = gc >> 10, cc = gc & (kNC - 1);
  const float* st = start + (size_t)gc * 8;
  const float4 s0 = reinterpret_cast<const float4*>(st)[0];
  const float4 s1 = reinterpret_cast<const float4*>(st)[1];
  float a[5] = {s0.x, s0.y, s0.z, s0.w, s1.x};
  float ls = s1.y;
  float ov[20];
  const uint4* ep = wsE + ((size_t)b * kT + (size_t)cc * kC) * 4;
#pragma unroll
  for (int k = 0; k < 4; ++k) {
    uint4 q0 = ep[k * 4], q1 = ep[k * 4 + 1], q2 = ep[k * 4 + 2], q3 = ep[k * 4 + 3];
    unsigned d[14] = {q0.x, q0.y, q0.z, q0.w, q1.x, q1.y, q1.z, q1.w,
                      q2.x, q2.y, q2.z, q2.w, q3.x, q3.y};
    float E[25];
#pragma unroll
    for (int q = 0; q < 12; ++q) {
      E[2 * q]     = __uint_as_float(d[q] << 16);
      E[2 * q + 1] = __uint_as_float(d[q] & 0xffff0000u);
    }
    E[24] = __uint_as_float(d[12] << 16);
    const float cst = __uint_as_float((d[12] >> 16) | (d[13] << 16));
    float o[5];
#pragma unroll
    for (int j = 0; j < 5; ++j) {
      float acc = a[0] * E[j];
      acc = fmaf(a[1], E[5 + j], acc);
      acc = fmaf(a[2], E[10 + j], acc);
      acc = fmaf(a[3], E[15 + j], acc);
      acc = fmaf(a[4], E[20 + j], acc);
      o[j] = acc;
    }
    ls += cst;
    float L[5];
#pragma unroll
    for (int j = 0; j < 5; ++j) L[j] = __log2f(o[j]);
#pragma unroll
    for (int j = 0; j < 5; ++j) ov[k * 5 + j] = (L[j] + ls) * kLn2;
    const float lm = max5(L[0], L[1], L[2], L[3], L[4]);
    const float m = fmaxf(max5(o[0], o[1], o[2], o[3], o[4]), 1e-30f);
    const float r = __builtin_amdgcn_rcpf(m);
#pragma unroll
    for (int j = 0; j < 5; ++j) a[j] = o[j] * r;
    ls += lm;
  }
  float4* w = reinterpret_cast<float4*>(outp + kB + ((size_t)b * kT + (size_t)cc * kC) * kS);
#pragma unroll
  for (int q = 0; q < 5; ++q)
    w[q] = make_float4(ov[q * 4], ov[q * 4 + 1], ov[q * 4 + 2], ov[q * 4 + 3]);
}

// fallback: rebuild E (row-streamed) when ws too small for wsE
__global__ __launch_bounds__(256, 3) void k_alpha_b(
    const float* __restrict__ obs, const float* __restrict__ feat,
    const float* __restrict__ P, const float* __restrict__ start,
    float* __restrict__ outp) {
  __shared__ __align__(16) float p[P_TOT];
  if (threadIdx.x < P_TOT / 4)
    reinterpret_cast<float4*>(p)[threadIdx.x] =
        reinterpret_cast<const float4*>(P)[threadIdx.x];
  __syncthreads();
  const int gc = blockIdx.x * 256 + threadIdx.x;
  const int b = gc >> 10, cc = gc & (kNC - 1);
  const size_t t0 = (size_t)b * kT + (size_t)cc * kC;
  const float* st = start + (size_t)gc * 8;
  const float4 s0 = reinterpret_cast<const float4*>(st)[0];
  const float4 s1 = reinterpret_cast<const float4*>(st)[1];
  float a[5] = {s0.x, s0.y, s0.z, s0.w, s1.x};
  float ls = s1.y;
#pragma unroll 1
  for (int k = 0; k < 4; ++k) {
    float E[25];
    float c;
    if (cc == 0 && k == 0) c = stepE0<false>(obs, p, b, E, nullptr);
    else c = stepE<0, false>(obs, feat, p, t0 + k, E, E, nullptr);
    float o[5];
#pragma unroll
    for (int j = 0; j < 5; ++j) {
      float acc = a[0] * E[j];
      acc = fmaf(a[1], E[5 + j], acc);
      acc = fmaf(a[2], E[10 + j], acc);
      acc = fmaf(a[3], E[15 + j], acc);
      acc = fmaf(a[4], E[20 + j], acc);
      o[j] = acc;
    }
    ls += c;
    float L[5];
#pragma unroll
    for (int j = 0; j < 5; ++j) L[j] = __log2f(o[j]);
    float* w = outp + kB + (t0 + k) * kS;
#pragma unroll
    for (int j = 0; j < 5; ++j) w[j] = (L[j] + ls) * kLn2;
    const float lm = max5(L[0], L[1], L[2], L[3], L[4]);
    const float m = fmaxf(max5(o[0], o[1], o[2], o[3], o[4]), 1e-30f);
    const float r = __builtin_amdgcn_rcpf(m);
#pragma unroll
    for (int j = 0; j < 5; ++j) a[j] = o[j] * r;
    ls += lm;
  }
}

}  // namespace

extern "C" void kernel_launch(void* const* d_in, const int* in_sizes, int n_in,
                              void* d_out, int out_size, void* d_ws, size_t ws_size,
                              hipStream_t stream) {
  (void)in_sizes; (void)n_in; (void)out_size;
  const float* obs   = (const float*)d_in[0];
  const float* feat  = (const float*)d_in[1];
  const float* means = (const float*)d_in[2];
  const float* lv    = (const float*)d_in[3];
  const float* linit = (const float*)d_in[4];
  const float* tbias = (const float*)d_in[5];
  const float* W1g   = (const float*)d_in[6];
  const float* b1g   = (const float*)d_in[7];
  const float* W2g   = (const float*)d_in[8];
  const float* b2g   = (const float*)d_in[9];
  float* out = (float*)d_out;

  // ws layout (floats): P 1024 | Rg kB*kNC*28 | start kB*kNC*8 | wsE (bytes)
  float* P     = (float*)d_ws;
  float* Rg    = P + P_RSV;
  float* start = Rg + (size_t)kB * kNC * 28;
  uint4* wsE   = reinterpret_cast<uint4*>(start + (size_t)kB * kNC * 8);
  const size_t needA = ((size_t)P_RSV + (size_t)kB * kNC * 28 + (size_t)kB * kNC * 8) * 4 +
                       (size_t)kB * kT * 64;
  const bool useA = ws_size >= needA;

  const int nBlk = (kB * kNC) / 256;  // 1024
  k_prep<<<1, 256, 0, stream>>>(means, lv, linit, tbias, W1g, b1g, W2g, b2g, P);
  if (useA) {
    k_build<true><<<nBlk, 256, 0, stream>>>(obs, feat, P, Rg, wsE);
  } else {
    k_build<false><<<nBlk, 256, 0, stream>>>(obs, feat, P, Rg, wsE);
  }
  k_scan<<<kB, 256, 0, stream>>>(Rg, start, out);
  if (useA) {
    k_alpha_a<<<nBlk, 256, 0, stream>>>(wsE, start, out);
  } else {
    k_alpha_b<<<nBlk, 256, 0, stream>>>(obs, feat, P, start, out);
  }
}

// Round 8
// 577.278 us; speedup vs baseline: 2.3446x; 2.3446x over previous
//
#include <hip/hip_runtime.h>
#include <math.h>

// MarketRegimeHMM forward via chunked associative scan — linear-domain semiring,
// base-2 scales.  R7: back to the R5 structure (single-t E build + immediate
// matmat fold; R6's row-streamed pointer-passed arrays went to scratch: 3GB
// traffic, 16x slowdown).  R5's spill is fixed by VECTORIZED param reads
// instead of pair-building: LDS layout padded so every param access is a
// float4/float2 (W2 rows of 12 with b2+bias folded into slot 10).  Live set
// ~100 floats -> no spill at 128 VGPR.
//
//   k_prep  : 1 block; preprocess params into the padded vector layout.
//   k_build : one lane per chunk (C=4), params in 3KB LDS, 4 straight-line
//             steps: buildE -> packE(bf16) -> matmat5 -> rescale.
//   k_scan  : one block per b: 3-level scan over 1024 records -> start, LL.
//   k_alpha : one lane per chunk: stream bf16 E, 25 FMA + 5 log2 per t.

namespace {

constexpr int kS = 5, kD = 16, kB = 256, kT = 4096;
constexpr int kC = 4, kNC = 1024;  // chunks per batch element

constexpr float kL2E = 1.4426950408889634f;  // 1/ln2
constexpr float kLn2 = 0.6931471805599453f;

// LDS/ws param layout (floats), all vector-read aligned:
constexpr int Q_MU = 0;    // 80  means                      [s*16+d]   float4
constexpr int Q_EA = 80;   // 80  -0.5*inv_v/ln2             [s*16+d]   float4
constexpr int Q_EC = 160;  // 5   -0.5*(16ln2pi+sum lv)/ln2  scalar
constexpr int Q_LN = 168;  // 5   log2_softmax(log_initial)  scalar
constexpr int Q_W1 = 176;  // 200 (2/ln2)*W1                 [(i*10+h)*4+f] float4
constexpr int Q_B1 = 376;  // 60  (2/ln2)*b1, rows of 12     [i*12+h]   f4,f4,f2
constexpr int Q_W2 = 436;  // 300 W2/ln2 rows of 12; slot10=(b2+tb)/ln2  3x float4
constexpr int P_TOT = 768;   // staged floats (3KB)
constexpr int P_RSV = 1024;  // reserved in ws

__device__ __forceinline__ float max5(float a0, float a1, float a2, float a3, float a4) {
  return fmaxf(fmaxf(fmaxf(a0, a1), fmaxf(a2, a3)), a4);
}

__device__ __forceinline__ void loadObs(const float* __restrict__ obs_bt, float* o) {
  const float4* o4 = reinterpret_cast<const float4*>(obs_bt);
  float4 v0 = o4[0], v1 = o4[1], v2 = o4[2], v3 = o4[3];
  o[0] = v0.x; o[1] = v0.y; o[2] = v0.z; o[3] = v0.w;
  o[4] = v1.x; o[5] = v1.y; o[6] = v1.z; o[7] = v1.w;
  o[8] = v2.x; o[9] = v2.y; o[10] = v2.z; o[11] = v2.w;
  o[12] = v3.x; o[13] = v3.y; o[14] = v3.z; o[15] = v3.w;
}

__device__ __forceinline__ unsigned bf16bits(float x) {
  unsigned u = __float_as_uint(x);
  return (u + 0x7fffu + ((u >> 16) & 1u)) >> 16;  // RTNE
}

__global__ void k_prep(const float* __restrict__ means, const float* __restrict__ lv,
                       const float* __restrict__ linit, const float* __restrict__ tbias,
                       const float* __restrict__ W1g, const float* __restrict__ b1g,
                       const float* __restrict__ W2g, const float* __restrict__ b2g,
                       float* __restrict__ P) {
  const int tid = threadIdx.x;  // 512
  if (tid < 80) {
    P[Q_MU + tid] = means[tid];
    P[Q_EA + tid] = -0.5f * kL2E * __expf(-lv[tid]);
  }
  if (tid >= 80 && tid < 85) {
    const int s = tid - 80;
    float acc = 0.f;
#pragma unroll
    for (int d = 0; d < 16; ++d) acc += lv[s * 16 + d];
    P[Q_EC + s] = -0.5f * kL2E * (29.406033062549525f + acc);  // 16*ln(2pi)+sum
    float l0 = linit[0], l1 = linit[1], l2 = linit[2], l3 = linit[3], l4 = linit[4];
    float m = max5(l0, l1, l2, l3, l4);
    float se = __expf(l0 - m) + __expf(l1 - m) + __expf(l2 - m) +
               __expf(l3 - m) + __expf(l4 - m);
    P[Q_LN + s] = kL2E * (linit[s] - (m + __logf(se)));
  }
  if (tid >= 85 && tid < 88) P[Q_EC + 80 + (tid - 85)] = 0.f;  // pad 165..167? no-op slots
  if (tid < 200) P[Q_W1 + tid] = (2.0f * kL2E) * W1g[tid];
  if (tid >= 200 && tid < 260) {  // B1 rows of 12
    const int i = tid - 200, r = i / 12, h = i - r * 12;
    P[Q_B1 + i] = (h < 10) ? (2.0f * kL2E) * b1g[r * 10 + h] : 0.f;
  }
  if (tid >= 260 && tid < 512) {
    // W2 rows of 12: slots 0..9 = W2/ln2, slot 10 = (b2+tbias)/ln2, slot 11 = 0
    for (int i = tid - 260; i < 300; i += 252) {
      const int r = i / 12, h = i - r * 12;
      float v;
      if (h < 10) v = kL2E * W2g[r * 10 + h];
      else if (h == 10) v = kL2E * (b2g[r] + tbias[r]);
      else v = 0.f;
      P[Q_W2 + i] = v;
    }
  }
  if (tid >= 88 && tid < 88 + (P_TOT - 736)) P[736 + tid - 88] = 0.f;  // tail pad
}

// E_t = softmax(logits) * diag(exp2(le - c)), c = max_j le[j] (log2 units).
// All param reads are broadcast float4/float2 ds_reads from LDS.
__device__ __forceinline__ void buildE(const float* __restrict__ obs,
                                       const float* __restrict__ feat,
                                       const float* __restrict__ p,
                                       size_t t, float E[25], float& c) {
  float o[16];
  loadObs(obs + t * kD, o);
  float le[5];
#pragma unroll
  for (int s = 0; s < 5; ++s) {
    float acc = p[Q_EC + s];
#pragma unroll
    for (int dq = 0; dq < 4; ++dq) {
      const float4 mu = *reinterpret_cast<const float4*>(p + Q_MU + s * 16 + dq * 4);
      const float4 ea = *reinterpret_cast<const float4*>(p + Q_EA + s * 16 + dq * 4);
      const float d0 = o[dq * 4 + 0] - mu.x, d1 = o[dq * 4 + 1] - mu.y;
      const float d2 = o[dq * 4 + 2] - mu.z, d3 = o[dq * 4 + 3] - mu.w;
      acc = fmaf(d0 * d0, ea.x, acc);
      acc = fmaf(d1 * d1, ea.y, acc);
      acc = fmaf(d2 * d2, ea.z, acc);
      acc = fmaf(d3 * d3, ea.w, acc);
    }
    le[s] = acc;
  }
  c = max5(le[0], le[1], le[2], le[3], le[4]);
  float eml[5];
#pragma unroll
  for (int j = 0; j < 5; ++j) eml[j] = exp2f(le[j] - c);
  const float4 f = *reinterpret_cast<const float4*>(feat + t * 4);
#pragma unroll
  for (int i = 0; i < 5; ++i) {
    const float4 bA = *reinterpret_cast<const float4*>(p + Q_B1 + i * 12);
    const float4 bB = *reinterpret_cast<const float4*>(p + Q_B1 + i * 12 + 4);
    const float2 bC = *reinterpret_cast<const float2*>(p + Q_B1 + i * 12 + 8);
    const float bb[10] = {bA.x, bA.y, bA.z, bA.w, bB.x, bB.y, bB.z, bB.w, bC.x, bC.y};
    float hv[10];
#pragma unroll
    for (int h = 0; h < 10; ++h) {
      const float4 w = *reinterpret_cast<const float4*>(p + Q_W1 + (i * 10 + h) * 4);
      float acc = bb[h];
      acc = fmaf(f.x, w.x, acc);
      acc = fmaf(f.y, w.y, acc);
      acc = fmaf(f.z, w.z, acc);
      acc = fmaf(f.w, w.w, acc);
      const float e = exp2f(acc);                            // = exp(2x)
      hv[h] = 1.f - 2.f * __builtin_amdgcn_rcpf(e + 1.f);    // tanh
    }
    float eg[5], se = 0.f;
#pragma unroll
    for (int j = 0; j < 5; ++j) {
      const float* wr = p + Q_W2 + (i * 5 + j) * 12;
      const float4 w0 = *reinterpret_cast<const float4*>(wr);
      const float4 w1 = *reinterpret_cast<const float4*>(wr + 4);
      const float4 w2 = *reinterpret_cast<const float4*>(wr + 8);  // x=w8 y=w9 z=b2 w=0
      float acc = w2.z;
      acc = fmaf(hv[0], w0.x, acc); acc = fmaf(hv[1], w0.y, acc);
      acc = fmaf(hv[2], w0.z, acc); acc = fmaf(hv[3], w0.w, acc);
      acc = fmaf(hv[4], w1.x, acc); acc = fmaf(hv[5], w1.y, acc);
      acc = fmaf(hv[6], w1.z, acc); acc = fmaf(hv[7], w1.w, acc);
      acc = fmaf(hv[8], w2.x, acc); acc = fmaf(hv[9], w2.y, acc);
      eg[j] = exp2f(acc);
      se += eg[j];
    }
    const float rs = __builtin_amdgcn_rcpf(se);
#pragma unroll
    for (int j = 0; j < 5; ++j) E[i * 5 + j] = eg[j] * rs * eml[j];
  }
}

// t=0 pseudo-record: all rows = linear alpha0 (log2-scaled by c)
__device__ __forceinline__ void buildE0(const float* __restrict__ obs,
                                        const float* __restrict__ p, int b,
                                        float E[25], float& c) {
  float o[16];
  loadObs(obs + (size_t)b * kT * kD, o);
  float v[5];
#pragma unroll
  for (int s = 0; s < 5; ++s) {
    float acc = p[Q_EC + s];
#pragma unroll
    for (int dq = 0; dq < 4; ++dq) {
      const float4 mu = *reinterpret_cast<const float4*>(p + Q_MU + s * 16 + dq * 4);
      const float4 ea = *reinterpret_cast<const float4*>(p + Q_EA + s * 16 + dq * 4);
      const float d0 = o[dq * 4 + 0] - mu.x, d1 = o[dq * 4 + 1] - mu.y;
      const float d2 = o[dq * 4 + 2] - mu.z, d3 = o[dq * 4 + 3] - mu.w;
      acc = fmaf(d0 * d0, ea.x, acc);
      acc = fmaf(d1 * d1, ea.y, acc);
      acc = fmaf(d2 * d2, ea.z, acc);
      acc = fmaf(d3 * d3, ea.w, acc);
    }
    v[s] = acc + p[Q_LN + s];
  }
  c = max5(v[0], v[1], v[2], v[3], v[4]);
  float e5[5];
#pragma unroll
  for (int j = 0; j < 5; ++j) e5[j] = 0.2f * exp2f(v[j] - c);
#pragma unroll
  for (int i = 0; i < 5; ++i)
#pragma unroll
    for (int j = 0; j < 5; ++j) E[i * 5 + j] = e5[j];
}

__device__ __forceinline__ void matmat5(float R[25], const float E[25]) {
#pragma unroll
  for (int i = 0; i < 5; ++i) {
    const float r0 = R[i * 5 + 0], r1 = R[i * 5 + 1], r2 = R[i * 5 + 2];
    const float r3 = R[i * 5 + 3], r4 = R[i * 5 + 4];
#pragma unroll
    for (int j = 0; j < 5; ++j) {
      float acc = r0 * E[j];
      acc = fmaf(r1, E[5 + j], acc);
      acc = fmaf(r2, E[10 + j], acc);
      acc = fmaf(r3, E[15 + j], acc);
      acc = fmaf(r4, E[20 + j], acc);
      R[i * 5 + j] = acc;
    }
  }
}

__device__ __forceinline__ void rescale25(float R[25], float& sc) {
  float m = R[0];
#pragma unroll
  for (int e = 1; e < 25; ++e) m = fmaxf(m, R[e]);
  m = fmaxf(m, 1e-30f);
  const float r = __builtin_amdgcn_rcpf(m);
#pragma unroll
  for (int e = 0; e < 25; ++e) R[e] *= r;
  sc += __log2f(m);
}

__device__ __forceinline__ void vecmat5(float a[5], const float M[25]) {
  float o[5];
#pragma unroll
  for (int j = 0; j < 5; ++j) {
    float acc = a[0] * M[j];
    acc = fmaf(a[1], M[5 + j], acc);
    acc = fmaf(a[2], M[10 + j], acc);
    acc = fmaf(a[3], M[15 + j], acc);
    acc = fmaf(a[4], M[20 + j], acc);
    o[j] = acc;
  }
#pragma unroll
  for (int j = 0; j < 5; ++j) a[j] = o[j];
}

__device__ __forceinline__ void rescale5(float a[5], float& ls) {
  const float m = fmaxf(max5(a[0], a[1], a[2], a[3], a[4]), 1e-30f);
  const float r = __builtin_amdgcn_rcpf(m);
#pragma unroll
  for (int j = 0; j < 5; ++j) a[j] *= r;
  ls += __log2f(m);
}

__device__ __forceinline__ void packE(uint4* __restrict__ wsE, size_t t,
                                      const float E[25], float c) {
  unsigned d[13];
#pragma unroll
  for (int q = 0; q < 12; ++q)
    d[q] = bf16bits(E[2 * q]) | (bf16bits(E[2 * q + 1]) << 16);
  const unsigned cb = __float_as_uint(c);
  d[12] = bf16bits(E[24]) | (cb << 16);
  uint4* wp = wsE + t * 4;
  wp[0] = make_uint4(d[0], d[1], d[2], d[3]);
  wp[1] = make_uint4(d[4], d[5], d[6], d[7]);
  wp[2] = make_uint4(d[8], d[9], d[10], d[11]);
  wp[3] = make_uint4(d[12], cb >> 16, 0u, 0u);
}

template <bool STORE_E>
__global__ __launch_bounds__(256, 2) void k_build(
    const float* __restrict__ obs, const float* __restrict__ feat,
    const float* __restrict__ P, float* __restrict__ Rg,
    uint4* __restrict__ wsE) {
  __shared__ __align__(16) float p[P_TOT];
  if (threadIdx.x < P_TOT / 4)
    reinterpret_cast<float4*>(p)[threadIdx.x] =
        reinterpret_cast<const float4*>(P)[threadIdx.x];
  __syncthreads();
  const int gc = blockIdx.x * 256 + threadIdx.x;  // chunk id
  const int b = gc >> 10, cc = gc & (kNC - 1);
  const size_t t0 = (size_t)b * kT + (size_t)cc * kC;
  float R[25], sc;
  {
    float c;
    if (cc == 0) buildE0(obs, p, b, R, c);
    else buildE(obs, feat, p, t0, R, c);
    sc = c;
    if (STORE_E) packE(wsE, t0, R, c);
  }
  {
    float E[25], c;
    buildE(obs, feat, p, t0 + 1, E, c);
    if (STORE_E) packE(wsE, t0 + 1, E, c);
    sc += c;
    matmat5(R, E);
    rescale25(R, sc);
  }
  {
    float E[25], c;
    buildE(obs, feat, p, t0 + 2, E, c);
    if (STORE_E) packE(wsE, t0 + 2, E, c);
    sc += c;
    matmat5(R, E);
    rescale25(R, sc);
  }
  {
    float E[25], c;
    buildE(obs, feat, p, t0 + 3, E, c);
    if (STORE_E) packE(wsE, t0 + 3, E, c);
    sc += c;
    matmat5(R, E);
    rescale25(R, sc);
  }
  float4* o4 = reinterpret_cast<float4*>(Rg + (size_t)gc * 28);
  o4[0] = make_float4(R[0], R[1], R[2], R[3]);
  o4[1] = make_float4(R[4], R[5], R[6], R[7]);
  o4[2] = make_float4(R[8], R[9], R[10], R[11]);
  o4[3] = make_float4(R[12], R[13], R[14], R[15]);
  o4[4] = make_float4(R[16], R[17], R[18], R[19]);
  o4[5] = make_float4(R[20], R[21], R[22], R[23]);
  o4[6] = make_float4(R[24], sc, 0.f, 0.f);
}

__device__ __forceinline__ void loadRec(const float* __restrict__ base, size_t rec,
                                        float M[25], float& msc) {
  const float4* src = reinterpret_cast<const float4*>(base + rec * 28);
  float4 q[7];
#pragma unroll
  for (int i = 0; i < 7; ++i) q[i] = src[i];
  const float* v = reinterpret_cast<const float*>(q);
#pragma unroll
  for (int e = 0; e < 25; ++e) M[e] = v[e];
  msc = v[25];
}

// 3-level scan over 1024 records per b -> start[b][c], LL[b].
__global__ __launch_bounds__(256) void k_scan(const float* __restrict__ Rg,
                                              float* __restrict__ start,
                                              float* __restrict__ out) {
  __shared__ float sA[256 * 29];
  __shared__ float sB[32 * 28];
  __shared__ float sPB[32 * 8];
  __shared__ float sPA[256 * 8];
  const int b = blockIdx.x, j = threadIdx.x;
  const float* Rb = Rg + (size_t)b * kNC * 28;
  float A[25], asc;
  loadRec(Rb, (size_t)(4 * j), A, asc);
#pragma unroll 1
  for (int k = 1; k < 4; ++k) {
    float M[25], msc;
    loadRec(Rb, (size_t)(4 * j + k), M, msc);
    asc += msc;
    matmat5(A, M);
    if (k >= 2) rescale25(A, asc);
  }
#pragma unroll
  for (int e = 0; e < 25; ++e) sA[j * 29 + e] = A[e];
  sA[j * 29 + 25] = asc;
  __syncthreads();
  if (j < 32) {
    float Bm[25], bsc;
#pragma unroll
    for (int e = 0; e < 25; ++e) Bm[e] = sA[(8 * j) * 29 + e];
    bsc = sA[(8 * j) * 29 + 25];
#pragma unroll 1
    for (int k = 1; k < 8; ++k) {
      float M[25];
#pragma unroll
      for (int e = 0; e < 25; ++e) M[e] = sA[(8 * j + k) * 29 + e];
      bsc += sA[(8 * j + k) * 29 + 25];
      matmat5(Bm, M);
      if (k & 1) rescale25(Bm, bsc);
    }
#pragma unroll
    for (int e = 0; e < 25; ++e) sB[j * 28 + e] = Bm[e];
    sB[j * 28 + 25] = bsc;
  }
  __syncthreads();
  if (j == 0) {
    float a[5] = {1.f, 1.f, 1.f, 1.f, 1.f};
    float ls = 0.f;
#pragma unroll 1
    for (int g = 0; g < 32; ++g) {
#pragma unroll
      for (int s = 0; s < 5; ++s) sPB[g * 8 + s] = a[s];
      sPB[g * 8 + 5] = ls;
      float M[25];
#pragma unroll
      for (int e = 0; e < 25; ++e) M[e] = sB[g * 28 + e];
      vecmat5(a, M);
      ls += sB[g * 28 + 25];
      rescale5(a, ls);
    }
    out[b] = (__log2f(a[0] + a[1] + a[2] + a[3] + a[4]) + ls) * kLn2;
  }
  __syncthreads();
  if (j < 32) {
    float a[5], ls;
#pragma unroll
    for (int s = 0; s < 5; ++s) a[s] = sPB[j * 8 + s];
    ls = sPB[j * 8 + 5];
#pragma unroll 1
    for (int q = 0; q < 8; ++q) {
      const int idx = 8 * j + q;
#pragma unroll
      for (int s = 0; s < 5; ++s) sPA[idx * 8 + s] = a[s];
      sPA[idx * 8 + 5] = ls;
      float M[25];
#pragma unroll
      for (int e = 0; e < 25; ++e) M[e] = sA[idx * 29 + e];
      vecmat5(a, M);
      ls += sA[idx * 29 + 25];
      rescale5(a, ls);
    }
  }
  __syncthreads();
  {
    float a[5], ls;
#pragma unroll
    for (int s = 0; s < 5; ++s) a[s] = sPA[j * 8 + s];
    ls = sPA[j * 8 + 5];
#pragma unroll 1
    for (int k = 0; k < 4; ++k) {
      const int r = 4 * j + k;
      float* st = start + ((size_t)b * kNC + r) * 8;
      reinterpret_cast<float4*>(st)[0] = make_float4(a[0], a[1], a[2], a[3]);
      reinterpret_cast<float4*>(st)[1] = make_float4(a[4], ls, 0.f, 0.f);
      float M[25], msc;
      loadRec(Rb, (size_t)r, M, msc);
      vecmat5(a, M);
      ls += msc;
      rescale5(a, ls);
    }
  }
}

// stream bf16 E records; one lane per chunk
__global__ __launch_bounds__(256) void k_alpha_a(const uint4* __restrict__ wsE,
                                                 const float* __restrict__ start,
                                                 float* __restrict__ outp) {
  const int gc = blockIdx.x * 256 + threadIdx.x;
  const int b = gc >> 10, cc = gc & (kNC - 1);
  const float* st = start + (size_t)gc * 8;
  const float4 s0 = reinterpret_cast<const float4*>(st)[0];
  const float4 s1 = reinterpret_cast<const float4*>(st)[1];
  float a[5] = {s0.x, s0.y, s0.z, s0.w, s1.x};
  float ls = s1.y;
  float ov[20];
  const uint4* ep = wsE + ((size_t)b * kT + (size_t)cc * kC) * 4;
#pragma unroll
  for (int k = 0; k < 4; ++k) {
    uint4 q0 = ep[k * 4], q1 = ep[k * 4 + 1], q2 = ep[k * 4 + 2], q3 = ep[k * 4 + 3];
    unsigned d[14] = {q0.x, q0.y, q0.z, q0.w, q1.x, q1.y, q1.z, q1.w,
                      q2.x, q2.y, q2.z, q2.w, q3.x, q3.y};
    float E[25];
#pragma unroll
    for (int q = 0; q < 12; ++q) {
      E[2 * q]     = __uint_as_float(d[q] << 16);
      E[2 * q + 1] = __uint_as_float(d[q] & 0xffff0000u);
    }
    E[24] = __uint_as_float(d[12] << 16);
    const float cst = __uint_as_float((d[12] >> 16) | (d[13] << 16));
    float o[5];
#pragma unroll
    for (int j = 0; j < 5; ++j) {
      float acc = a[0] * E[j];
      acc = fmaf(a[1], E[5 + j], acc);
      acc = fmaf(a[2], E[10 + j], acc);
      acc = fmaf(a[3], E[15 + j], acc);
      acc = fmaf(a[4], E[20 + j], acc);
      o[j] = acc;
    }
    ls += cst;
    float L[5];
#pragma unroll
    for (int j = 0; j < 5; ++j) L[j] = __log2f(o[j]);
#pragma unroll
    for (int j = 0; j < 5; ++j) ov[k * 5 + j] = (L[j] + ls) * kLn2;
    const float lm = max5(L[0], L[1], L[2], L[3], L[4]);
    const float m = fmaxf(max5(o[0], o[1], o[2], o[3], o[4]), 1e-30f);
    const float r = __builtin_amdgcn_rcpf(m);
#pragma unroll
    for (int j = 0; j < 5; ++j) a[j] = o[j] * r;
    ls += lm;
  }
  float4* w = reinterpret_cast<float4*>(outp + kB + ((size_t)b * kT + (size_t)cc * kC) * kS);
#pragma unroll
  for (int q = 0; q < 5; ++q)
    w[q] = make_float4(ov[q * 4], ov[q * 4 + 1], ov[q * 4 + 2], ov[q * 4 + 3]);
}

// fallback: rebuild E when ws too small for wsE
__global__ __launch_bounds__(256, 2) void k_alpha_b(
    const float* __restrict__ obs, const float* __restrict__ feat,
    const float* __restrict__ P, const float* __restrict__ start,
    float* __restrict__ outp) {
  __shared__ __align__(16) float p[P_TOT];
  if (threadIdx.x < P_TOT / 4)
    reinterpret_cast<float4*>(p)[threadIdx.x] =
        reinterpret_cast<const float4*>(P)[threadIdx.x];
  __syncthreads();
  const int gc = blockIdx.x * 256 + threadIdx.x;
  const int b = gc >> 10, cc = gc & (kNC - 1);
  const size_t t0 = (size_t)b * kT + (size_t)cc * kC;
  const float* st = start + (size_t)gc * 8;
  const float4 s0 = reinterpret_cast<const float4*>(st)[0];
  const float4 s1 = reinterpret_cast<const float4*>(st)[1];
  float a[5] = {s0.x, s0.y, s0.z, s0.w, s1.x};
  float ls = s1.y;
#pragma unroll 1
  for (int k = 0; k < 4; ++k) {
    float E[25], c;
    if (cc == 0 && k == 0) buildE0(obs, p, b, E, c);
    else buildE(obs, feat, p, t0 + k, E, c);
    float o[5];
#pragma unroll
    for (int j = 0; j < 5; ++j) {
      float acc = a[0] * E[j];
      acc = fmaf(a[1], E[5 + j], acc);
      acc = fmaf(a[2], E[10 + j], acc);
      acc = fmaf(a[3], E[15 + j], acc);
      acc = fmaf(a[4], E[20 + j], acc);
      o[j] = acc;
    }
    ls += c;
    float L[5];
#pragma unroll
    for (int j = 0; j < 5; ++j) L[j] = __log2f(o[j]);
    float* w = outp + kB + (t0 + k) * kS;
#pragma unroll
    for (int j = 0; j < 5; ++j) w[j] = (L[j] + ls) * kLn2;
    const float lm = max5(L[0], L[1], L[2], L[3], L[4]);
    const float m = fmaxf(max5(o[0], o[1], o[2], o[3], o[4]), 1e-30f);
    const float r = __builtin_amdgcn_rcpf(m);
#pragma unroll
    for (int j = 0; j < 5; ++j) a[j] = o[j] * r;
    ls += lm;
  }
}

}  // namespace

extern "C" void kernel_launch(void* const* d_in, const int* in_sizes, int n_in,
                              void* d_out, int out_size, void* d_ws, size_t ws_size,
                              hipStream_t stream) {
  (void)in_sizes; (void)n_in; (void)out_size;
  const float* obs   = (const float*)d_in[0];
  const float* feat  = (const float*)d_in[1];
  const float* means = (const float*)d_in[2];
  const float* lv    = (const float*)d_in[3];
  const float* linit = (const float*)d_in[4];
  const float* tbias = (const float*)d_in[5];
  const float* W1g   = (const float*)d_in[6];
  const float* b1g   = (const float*)d_in[7];
  const float* W2g   = (const float*)d_in[8];
  const float* b2g   = (const float*)d_in[9];
  float* out = (float*)d_out;

  // ws layout (floats): P 1024 | Rg kB*kNC*28 | start kB*kNC*8 | wsE (bytes)
  float* P     = (float*)d_ws;
  float* Rg    = P + P_RSV;
  float* start = Rg + (size_t)kB * kNC * 28;
  uint4* wsE   = reinterpret_cast<uint4*>(start + (size_t)kB * kNC * 8);
  const size_t needA = ((size_t)P_RSV + (size_t)kB * kNC * 28 + (size_t)kB * kNC * 8) * 4 +
                       (size_t)kB * kT * 64;
  const bool useA = ws_size >= needA;

  const int nBlk = (kB * kNC) / 256;  // 1024
  k_prep<<<1, 512, 0, stream>>>(means, lv, linit, tbias, W1g, b1g, W2g, b2g, P);
  if (useA) {
    k_build<true><<<nBlk, 256, 0, stream>>>(obs, feat, P, Rg, wsE);
  } else {
    k_build<false><<<nBlk, 256, 0, stream>>>(obs, feat, P, Rg, wsE);
  }
  k_scan<<<kB, 256, 0, stream>>>(Rg, start, out);
  if (useA) {
    k_alpha_a<<<nBlk, 256, 0, stream>>>(wsE, start, out);
  } else {
    k_alpha_b<<<nBlk, 256, 0, stream>>>(obs, feat, P, start, out);
  }
}